// Round 1
// baseline (8270.947 us; speedup 1.0000x reference)
//
#include <hip/hip_runtime.h>
#include <stdint.h>
#include <stddef.h>

#define TT   128
#define BB   1024
#define INN  75
#define HH   128
#define KXP  96
#define OUTN 256
#define DECN 9600
#define NBLK 32
#define EPSB 1e-5f

typedef short v8s __attribute__((ext_vector_type(8)));   // 8 bf16 (4 VGPR) MFMA frag
typedef float v4f __attribute__((ext_vector_type(4)));   // 4 fp32 acc frag
typedef unsigned short ush;
typedef unsigned int   u32;

// ---- static device workspace (rewritten fully on every launch; no d_ws use) ----
__device__ __align__(256) ush g_xpad[(size_t)TT * BB * KXP];    // x padded to K=96, bf16, [t][b][k]
__device__ __align__(256) ush g_hs0[(size_t)TT * BB * HH];      // layer0 h stream, [t][b][u]
__device__ __align__(256) ush g_hb1[2][BB * HH];                // layer1 h ping-pong
__device__ __align__(256) ush g_wtih0[NBLK][16][KXP];           // gathered W^T slices (col-major per block)
__device__ __align__(256) ush g_wthh0[NBLK][16][HH];
__device__ __align__(256) ush g_wtih1[NBLK][16][HH];
__device__ __align__(256) ush g_wthh1[NBLK][16][HH];
__device__ __align__(256) ush g_fcwt[OUTN][HH];                 // fc_w^T bf16
__device__ __align__(256) ush g_decwt[DECN][OUTN];              // dec_w^T bf16
__device__ __align__(256) ush g_emb[BB][OUTN];                  // fc output bf16
__device__ __align__(256) u32 g_ctr[64];                        // barrier counters (L0 at [0], L1 at [32])

// ---- helpers ----
__device__ __forceinline__ ush f2bf(float f) {
  u32 u = __float_as_uint(f);
  u32 r = (u + 0x7FFFu + ((u >> 16) & 1u)) >> 16;   // RNE
  return (ush)r;
}
__device__ __forceinline__ float bf2f(ush u) { return __uint_as_float(((u32)u) << 16); }
__device__ __forceinline__ u32 packbf2(float a, float b) {
  return (u32)f2bf(a) | ((u32)f2bf(b) << 16);
}
__device__ __forceinline__ float sigf(float x)  { return 1.f / (1.f + __expf(-x)); }
__device__ __forceinline__ float tanhf_(float x){ float e = __expf(2.f * x); return 1.f - 2.f / (e + 1.f); }
__device__ __forceinline__ v8s ld8(const ush* p) { return *reinterpret_cast<const v8s*>(p); }

// ---- prep kernels ----
__global__ void kzero() {
  int idx = blockIdx.x * blockDim.x + threadIdx.x;        // grid 512x256 = 131072
  u32* p = reinterpret_cast<u32*>(&g_hb1[0][0]);
  if (idx < (2 * BB * HH) / 2) p[idx] = 0u;
  if (blockIdx.x == 0 && threadIdx.x < 64) g_ctr[threadIdx.x] = 0u;
}

__global__ void kpackx(const float* __restrict__ seq) {
  int idx = blockIdx.x * 256 + threadIdx.x;               // < TT*BB*KXP
  int kk = idx % KXP; int rest = idx / KXP;
  int b = rest % BB;  int t = rest / BB;
  float v = (kk < INN) ? seq[((size_t)b * TT + t) * INN + kk] : 0.f;
  g_xpad[idx] = f2bf(v);
}

__global__ void kpackw(const float* __restrict__ Wih0, const float* __restrict__ Whh0,
                       const float* __restrict__ Wih1, const float* __restrict__ Whh1,
                       const float* __restrict__ fcw,  const float* __restrict__ decw) {
  int idx = blockIdx.x * 256 + threadIdx.x;               // < 2736128 (grid 10688)
  if (idx < 49152) {                                      // WTih0 : 32*16*96
    int kk = idx % KXP; int r = idx / KXP; int nn = r % 16; int nb = r / 16;
    int col = (nn >> 2) * HH + nb * 4 + (nn & 3);
    g_wtih0[nb][nn][kk] = f2bf((kk < INN) ? Wih0[kk * 512 + col] : 0.f);
  } else if (idx < 114688) {                              // WThh0 : 32*16*128
    int j = idx - 49152; int kk = j % HH; int r = j / HH; int nn = r % 16; int nb = r / 16;
    int col = (nn >> 2) * HH + nb * 4 + (nn & 3);
    g_wthh0[nb][nn][kk] = f2bf(Whh0[kk * 512 + col]);
  } else if (idx < 180224) {                              // WTih1
    int j = idx - 114688; int kk = j % HH; int r = j / HH; int nn = r % 16; int nb = r / 16;
    int col = (nn >> 2) * HH + nb * 4 + (nn & 3);
    g_wtih1[nb][nn][kk] = f2bf(Wih1[kk * 512 + col]);
  } else if (idx < 245760) {                              // WThh1
    int j = idx - 180224; int kk = j % HH; int r = j / HH; int nn = r % 16; int nb = r / 16;
    int col = (nn >> 2) * HH + nb * 4 + (nn & 3);
    g_wthh1[nb][nn][kk] = f2bf(Whh1[kk * 512 + col]);
  } else if (idx < 278528) {                              // fc_w^T : 256*128
    int j = idx - 245760; int n = j % OUTN; int k = j / OUTN;
    g_fcwt[n][k] = f2bf(fcw[k * OUTN + n]);
  } else if (idx < 2736128) {                             // dec_w^T : 9600*256 (reads coalesced in n)
    int j = idx - 278528; int n = j % DECN; int k = j / DECN;
    g_decwt[n][k] = f2bf(decw[(size_t)k * DECN + n]);
  }
}

// ---- persistent recurrent kernel: 32 blocks x 256 thr; block owns 4 hidden units ----
template <int L>
__global__ __launch_bounds__(256, 1) void krec(
    const float* __restrict__ gih, const float* __restrict__ bih,
    const float* __restrict__ ghh, const float* __restrict__ bhh,
    const float* __restrict__ gc,  const float* __restrict__ bc,
    const float* __restrict__ bvec) {
  constexpr int KA = (L == 0) ? KXP : HH;
  constexpr int KS = KA / 32;
  const int tid = threadIdx.x;
  const int w = tid >> 6, l = tid & 63;
  const int lm = l & 15, lq = l >> 4;
  const int nb = blockIdx.x, u0 = nb * 4;
  const int jj = lm & 3, kk4 = lm >> 2;   // pointwise: unit jj, mt-quarter kk4

  __shared__ u32   gbufh[4][16][136];     // per-wave gate exchange, bf16-pair packed (~35 KB)
  __shared__ float sred[4][16][4];
  __shared__ float sbc[16][4];
  __shared__ float credw[4][4][2];

  const ush* const Abase = (L == 0) ? g_xpad : g_hs0;
  const ush* const WTih  = (L == 0) ? &g_wtih0[nb][0][0] : &g_wtih1[nb][0][0];
  const ush* const WThh  = (L == 0) ? &g_wthh0[nb][0][0] : &g_wthh1[nb][0][0];

  // B-fragments live in registers for all 128 steps
  v8s bfi[KS], bfh[4];
#pragma unroll
  for (int ks = 0; ks < KS; ++ks) bfi[ks] = ld8(WTih + lm * KA + ks * 32 + lq * 8);
#pragma unroll
  for (int ks = 0; ks < 4; ++ks)  bfh[ks] = ld8(WThh + lm * HH + ks * 32 + lq * 8);

  float cst[16];
#pragma unroll
  for (int i = 0; i < 16; ++i) cst[i] = 0.f;
  const float gcj = gc[u0 + jj], bcj = bc[u0 + jj];

  const v4f vz = {0.f, 0.f, 0.f, 0.f};
  u32 target = 0;

  for (int t = 0; t < TT; ++t) {
    v4f aih[16], ahh[16];
#pragma unroll
    for (int mt = 0; mt < 16; ++mt) { aih[mt] = vz; ahh[mt] = vz; }

    { // GEMM1: input-hidden (x_t or hs0[t]) for this block's 16 gate cols
      const ush* Ax = Abase + (size_t)t * BB * KA + (size_t)(w * 256 + lm) * KA + lq * 8;
#pragma unroll
      for (int mt = 0; mt < 16; ++mt) {
        const ush* ap = Ax + (size_t)mt * 16 * KA;
#pragma unroll
        for (int ks = 0; ks < KS; ++ks)
          aih[mt] = __builtin_amdgcn_mfma_f32_16x16x32_bf16(ld8(ap + ks * 32), bfi[ks], aih[mt], 0, 0, 0);
      }
    }
    if ((L == 1) || (t > 0)) { // GEMM2: hidden-hidden
      const ush* Hp = (L == 0) ? (g_hs0 + (size_t)(t - 1) * BB * HH) : &g_hb1[t & 1][0];
      const ush* hx = Hp + (size_t)(w * 256 + lm) * HH + lq * 8;
#pragma unroll
      for (int mt = 0; mt < 16; ++mt) {
        const ush* hp = hx + (size_t)mt * 16 * HH;
#pragma unroll
        for (int ks = 0; ks < 4; ++ks)
          ahh[mt] = __builtin_amdgcn_mfma_f32_16x16x32_bf16(ld8(hp + ks * 32), bfh[ks], ahh[mt], 0, 0, 0);
      }
    }

    // per-column batch stats (block-local: block owns these 16 gate columns)
    float si = 0.f, qi = 0.f, sh = 0.f, qh = 0.f;
#pragma unroll
    for (int mt = 0; mt < 16; ++mt)
#pragma unroll
      for (int r = 0; r < 4; ++r) {
        float a = aih[mt][r], b = ahh[mt][r];
        si += a; qi += a * a; sh += b; qh += b * b;
      }
#pragma unroll
    for (int off = 16; off < 64; off <<= 1) {
      si += __shfl_xor(si, off); qi += __shfl_xor(qi, off);
      sh += __shfl_xor(sh, off); qh += __shfl_xor(qh, off);
    }
    if (l < 16) { sred[w][l][0] = si; sred[w][l][1] = qi; sred[w][l][2] = sh; sred[w][l][3] = qh; }
    __syncthreads();
    if (tid < 16) {
      float S = 0.f, Q = 0.f, S2 = 0.f, Q2 = 0.f;
#pragma unroll
      for (int ww = 0; ww < 4; ++ww) {
        S += sred[ww][tid][0]; Q += sred[ww][tid][1];
        S2 += sred[ww][tid][2]; Q2 += sred[ww][tid][3];
      }
      const int colg = (tid >> 2) * HH + u0 + (tid & 3);
      float mi = S * (1.f / BB), va = Q * (1.f / BB) - mi * mi, rs = rsqrtf(va + EPSB);
      float ai = gih[colg] * rs;
      float mh = S2 * (1.f / BB), vb = Q2 * (1.f / BB) - mh * mh, rs2 = rsqrtf(vb + EPSB);
      float ah = ghh[colg] * rs2;
      sbc[tid][0] = ai; sbc[tid][1] = bih[colg] - ai * mi + bvec[colg];
      sbc[tid][2] = ah; sbc[tid][3] = bhh[colg] - ah * mh;
    }
    __syncthreads();

    // apply BN, pack gates bf16-pairs into LDS in [col][row-pair] layout
    const float Ai = sbc[lm][0], Di = sbc[lm][1], Ah = sbc[lm][2], Dh = sbc[lm][3];
#pragma unroll
    for (int mt = 0; mt < 16; ++mt) {
      float g0 = aih[mt][0] * Ai + Di + ahh[mt][0] * Ah + Dh;
      float g1 = aih[mt][1] * Ai + Di + ahh[mt][1] * Ah + Dh;
      float g2 = aih[mt][2] * Ai + Di + ahh[mt][2] * Ah + Dh;
      float g3 = aih[mt][3] * Ai + Di + ahh[mt][3] * Ah + Dh;
      uint2 pk; pk.x = packbf2(g0, g1); pk.y = packbf2(g2, g3);
      *reinterpret_cast<uint2*>(&gbufh[w][lm][mt * 8 + lq * 2]) = pk;
    }
    __syncthreads();

    // pointwise LSTM cell: lane handles unit jj, rows (4*kk4+m)*16 + lq*4 + r
    float csum = 0.f, cqs = 0.f;
    float so[16];
#pragma unroll
    for (int m = 0; m < 4; ++m) {
      const int rp = (kk4 * 4 + m) * 8 + lq * 2;
      uint2 pf = *reinterpret_cast<uint2*>(&gbufh[w][jj][rp]);
      uint2 pi = *reinterpret_cast<uint2*>(&gbufh[w][jj + 4][rp]);
      uint2 po = *reinterpret_cast<uint2*>(&gbufh[w][jj + 8][rp]);
      uint2 pg = *reinterpret_cast<uint2*>(&gbufh[w][jj + 12][rp]);
      float fv[4] = { bf2f((ush)pf.x), bf2f((ush)(pf.x >> 16)), bf2f((ush)pf.y), bf2f((ush)(pf.y >> 16)) };
      float iv[4] = { bf2f((ush)pi.x), bf2f((ush)(pi.x >> 16)), bf2f((ush)pi.y), bf2f((ush)(pi.y >> 16)) };
      float ov[4] = { bf2f((ush)po.x), bf2f((ush)(po.x >> 16)), bf2f((ush)po.y), bf2f((ush)(po.y >> 16)) };
      float gv[4] = { bf2f((ush)pg.x), bf2f((ush)(pg.x >> 16)), bf2f((ush)pg.y), bf2f((ush)(pg.y >> 16)) };
#pragma unroll
      for (int r = 0; r < 4; ++r) {
        float c1 = sigf(fv[r]) * cst[m * 4 + r] + sigf(iv[r]) * tanhf_(gv[r]);
        cst[m * 4 + r] = c1;
        so[m * 4 + r] = sigf(ov[r]);
        csum += c1; cqs += c1 * c1;
      }
    }
    // reduce c1 stats over the 16 lanes sharing unit jj
    csum += __shfl_xor(csum, 4);  cqs += __shfl_xor(cqs, 4);
    csum += __shfl_xor(csum, 8);  cqs += __shfl_xor(cqs, 8);
    csum += __shfl_xor(csum, 16); cqs += __shfl_xor(cqs, 16);
    csum += __shfl_xor(csum, 32); cqs += __shfl_xor(cqs, 32);
    if (l < 4) { credw[w][l][0] = csum; credw[w][l][1] = cqs; }
    __syncthreads();
    float S = 0.f, Q = 0.f;
#pragma unroll
    for (int ww = 0; ww < 4; ++ww) { S += credw[ww][jj][0]; Q += credw[ww][jj][1]; }
    {
      float mc = S * (1.f / BB), vc = Q * (1.f / BB) - mc * mc, rs = rsqrtf(vc + EPSB);
      float ac = gcj * rs, dc = bcj - ac * mc;
      ush* Hd = ((L == 0) ? (g_hs0 + (size_t)t * BB * HH) : &g_hb1[(t + 1) & 1][0]) + u0 + jj;
#pragma unroll
      for (int m = 0; m < 4; ++m)
#pragma unroll
        for (int r = 0; r < 4; ++r) {
          int row = w * 256 + (kk4 * 4 + m) * 16 + lq * 4 + r;
          float h1 = so[m * 4 + r] * tanhf_(cst[m * 4 + r] * ac + dc);
          Hd[(size_t)row * HH] = f2bf(h1);
        }
    }

    // ---- grid barrier (32 blocks co-resident; device-scope counter) ----
    target += NBLK;
    __syncthreads();
    __threadfence();
    if (tid == 0) {
      __hip_atomic_fetch_add(&g_ctr[L * 32], 1u, __ATOMIC_RELAXED, __HIP_MEMORY_SCOPE_AGENT);
      while (__hip_atomic_load(&g_ctr[L * 32], __ATOMIC_RELAXED, __HIP_MEMORY_SCOPE_AGENT) < target)
        __builtin_amdgcn_s_sleep(1);
    }
    __syncthreads();
    __threadfence();
  }
}

// ---- epilogue: emb = h_last @ fc_w + fc_b (bf16 out) ----
__global__ __launch_bounds__(256) void kfc(const float* __restrict__ fcb) {
  const int tid = threadIdx.x, w = tid >> 6, l = tid & 63;
  const int lm = l & 15, lq = l >> 4;
  const int col = blockIdx.x * 16 + lm;   // grid 16
  v8s bf[4];
#pragma unroll
  for (int ks = 0; ks < 4; ++ks) bf[ks] = ld8(&g_fcwt[col][ks * 32 + lq * 8]);
  const float bias = fcb[col];
  const v4f vz = {0.f, 0.f, 0.f, 0.f};
#pragma unroll
  for (int mt = 0; mt < 16; ++mt) {
    const int rowa = w * 256 + mt * 16 + lm;
    const ush* ap = &g_hb1[0][(size_t)rowa * HH] + lq * 8;
    v4f acc = vz;
#pragma unroll
    for (int ks = 0; ks < 4; ++ks)
      acc = __builtin_amdgcn_mfma_f32_16x16x32_bf16(ld8(ap + ks * 32), bf[ks], acc, 0, 0, 0);
#pragma unroll
    for (int r = 0; r < 4; ++r) {
      int row = w * 256 + mt * 16 + lq * 4 + r;
      g_emb[row][col] = f2bf(acc[r] + bias);
    }
  }
}

// ---- epilogue: out = emb @ dec_w + dec_b (fp32 out) ----
__global__ __launch_bounds__(256) void kdec(const float* __restrict__ decb, float* __restrict__ out) {
  const int tid = threadIdx.x, w = tid >> 6, l = tid & 63;
  const int lm = l & 15, lq = l >> 4;
  const int col = blockIdx.x * 16 + lm;   // grid 600
  v8s bf[8];
#pragma unroll
  for (int ks = 0; ks < 8; ++ks) bf[ks] = ld8(&g_decwt[col][ks * 32 + lq * 8]);
  const float bias = decb[col];
  const v4f vz = {0.f, 0.f, 0.f, 0.f};
#pragma unroll
  for (int mt = 0; mt < 16; ++mt) {
    const int rowa = w * 256 + mt * 16 + lm;
    const ush* ap = &g_emb[rowa][0] + lq * 8;
    v4f acc = vz;
#pragma unroll
    for (int ks = 0; ks < 8; ++ks)
      acc = __builtin_amdgcn_mfma_f32_16x16x32_bf16(ld8(ap + ks * 32), bf[ks], acc, 0, 0, 0);
#pragma unroll
    for (int r = 0; r < 4; ++r) {
      int row = w * 256 + mt * 16 + lq * 4 + r;
      out[(size_t)row * DECN + col] = acc[r] + bias;
    }
  }
}

extern "C" void kernel_launch(void* const* d_in, const int* in_sizes, int n_in,
                              void* d_out, int out_size, void* d_ws, size_t ws_size,
                              hipStream_t stream) {
  const float* seq  = (const float*)d_in[0];
  const float* Wih0 = (const float*)d_in[1];
  const float* Whh0 = (const float*)d_in[2];
  const float* b0   = (const float*)d_in[3];
  const float* gih0 = (const float*)d_in[4];
  const float* bih0 = (const float*)d_in[5];
  const float* ghh0 = (const float*)d_in[6];
  const float* bhh0 = (const float*)d_in[7];
  const float* gc0  = (const float*)d_in[8];
  const float* bc0  = (const float*)d_in[9];
  const float* Wih1 = (const float*)d_in[10];
  const float* Whh1 = (const float*)d_in[11];
  const float* b1   = (const float*)d_in[12];
  const float* gih1 = (const float*)d_in[13];
  const float* bih1 = (const float*)d_in[14];
  const float* ghh1 = (const float*)d_in[15];
  const float* bhh1 = (const float*)d_in[16];
  const float* gc1  = (const float*)d_in[17];
  const float* bc1  = (const float*)d_in[18];
  const float* fcw  = (const float*)d_in[19];
  const float* fcb  = (const float*)d_in[20];
  const float* decw = (const float*)d_in[21];
  const float* decb = (const float*)d_in[22];
  float* out = (float*)d_out;
  (void)in_sizes; (void)n_in; (void)out_size; (void)d_ws; (void)ws_size;

  kzero<<<dim3(512), dim3(256), 0, stream>>>();
  kpackx<<<dim3((TT * BB * KXP) / 256), dim3(256), 0, stream>>>(seq);
  kpackw<<<dim3(10688), dim3(256), 0, stream>>>(Wih0, Whh0, Wih1, Whh1, fcw, decw);
  krec<0><<<dim3(NBLK), dim3(256), 0, stream>>>(gih0, bih0, ghh0, bhh0, gc0, bc0, b0);
  krec<1><<<dim3(NBLK), dim3(256), 0, stream>>>(gih1, bih1, ghh1, bhh1, gc1, bc1, b1);
  kfc<<<dim3(16), dim3(256), 0, stream>>>(fcb);
  kdec<<<dim3(600), dim3(256), 0, stream>>>(decb, out);
}

// Round 2
// 5541.138 us; speedup vs baseline: 1.4926x; 1.4926x over previous
//
#include <hip/hip_runtime.h>
#include <stdint.h>
#include <stddef.h>

#define TT   128
#define BB   1024
#define INN  75
#define HH   128
#define KXP  96
#define OUTN 256
#define DECN 9600
#define NBLK 32
#define ROWS 32
#define EPSB 1e-5f

typedef short v8s __attribute__((ext_vector_type(8)));   // 8 bf16 (4 VGPR) MFMA frag
typedef float v4f __attribute__((ext_vector_type(4)));   // 4 fp32 acc frag
typedef unsigned short ush;
typedef unsigned int   u32;

// ---- static device workspace ----
__device__ __align__(256) ush g_xpad[(size_t)TT * BB * KXP];      // x padded to K=96, bf16, [t][b][k]
__device__ __align__(256) ush g_G1c[(size_t)TT * 512 * BB];       // precomputed BN(x@Wih0)+b0, [t][col][row] bf16
__device__ __align__(256) ush g_wtih0[512 * KXP];                 // W^T layouts: [col][k] bf16
__device__ __align__(256) ush g_wthh0[512 * HH];
__device__ __align__(256) ush g_wtih1[512 * HH];
__device__ __align__(256) ush g_wthh1[512 * HH];
__device__ __align__(256) ush g_fcwt[OUTN * HH];                  // fc_w^T [col][k]
__device__ __align__(256) ush g_decwt[(size_t)DECN * OUTN];       // dec_w^T [col][k]
__device__ __align__(256) ush g_hlast[BB * HH];                   // final h1(T-1), [row][u] bf16
__device__ __align__(256) ush g_emb[BB * OUTN];                   // fc output bf16
__device__ __align__(256) float g_stats[2][4096];                 // [parity][stream*1024+col*2 | 3072+layer*256+u*2]
__device__ __align__(256) u32 g_ctr2[2 * (TT + 1) + 2];           // per-step barrier counters

// ---- helpers ----
__device__ __forceinline__ ush f2bf(float f) {
  u32 u = __float_as_uint(f);
  u32 r = (u + 0x7FFFu + ((u >> 16) & 1u)) >> 16;   // RNE
  return (ush)r;
}
__device__ __forceinline__ float bf2f(ush u) { return __uint_as_float(((u32)u) << 16); }
__device__ __forceinline__ float sigf(float x)  { return 1.f / (1.f + __expf(-x)); }
__device__ __forceinline__ float tanhf_(float x){ float e = __expf(2.f * x); return 1.f - 2.f / (e + 1.f); }
__device__ __forceinline__ v8s ld8(const ush* p) { return *reinterpret_cast<const v8s*>(p); }
__device__ __forceinline__ float sload(const float* p) {
  return __hip_atomic_load(p, __ATOMIC_RELAXED, __HIP_MEMORY_SCOPE_AGENT);
}
__device__ __forceinline__ void sadd(float* p, float v) {
  __hip_atomic_fetch_add(p, v, __ATOMIC_RELAXED, __HIP_MEMORY_SCOPE_AGENT);
}
__device__ __forceinline__ void szero(float* p) {
  __hip_atomic_store(p, 0.f, __ATOMIC_RELAXED, __HIP_MEMORY_SCOPE_AGENT);
}

// ---- prep kernels ----
__global__ void kzero() {
  int idx = blockIdx.x * 256 + threadIdx.x;  // grid 32
  if (idx < 8192) ((float*)g_stats)[idx] = 0.f;
  if (idx < 2 * (TT + 1) + 2) g_ctr2[idx] = 0u;
}

__global__ void kpackx(const float* __restrict__ seq) {
  int idx = blockIdx.x * 256 + threadIdx.x;               // < TT*BB*KXP
  int kk = idx % KXP; int rest = idx / KXP;
  int b = rest % BB;  int t = rest / BB;
  float v = (kk < INN) ? seq[((size_t)b * TT + t) * INN + kk] : 0.f;
  g_xpad[idx] = f2bf(v);
}

__global__ void kpackw(const float* __restrict__ Wih0, const float* __restrict__ Whh0,
                       const float* __restrict__ Wih1, const float* __restrict__ Whh1,
                       const float* __restrict__ fcw,  const float* __restrict__ decw) {
  int idx = blockIdx.x * 256 + threadIdx.x;               // < 2736128 (grid 10688)
  if (idx < 49152) {                                      // wtih0: [c][96]
    int c = idx / KXP, k = idx % KXP;
    g_wtih0[idx] = f2bf((k < INN) ? Wih0[k * 512 + c] : 0.f);
  } else if (idx < 114688) {
    int j = idx - 49152; int c = j / HH, k = j % HH;
    g_wthh0[j] = f2bf(Whh0[k * 512 + c]);
  } else if (idx < 180224) {
    int j = idx - 114688; int c = j / HH, k = j % HH;
    g_wtih1[j] = f2bf(Wih1[k * 512 + c]);
  } else if (idx < 245760) {
    int j = idx - 180224; int c = j / HH, k = j % HH;
    g_wthh1[j] = f2bf(Whh1[k * 512 + c]);
  } else if (idx < 278528) {                              // fcwt [c][128]
    int j = idx - 245760; int c = j / HH, k = j % HH;
    g_fcwt[j] = f2bf(fcw[k * OUTN + c]);
  } else {                                                // decwt [c][256], coalesced reads
    int j = idx - 278528; int n = j % DECN, k = j / DECN;
    g_decwt[(size_t)n * OUTN + k] = f2bf(decw[(size_t)k * DECN + n]);
  }
}

// G1c[t][col][row] = BN_ih0(x_t @ Wih0)[col] + b0[col], batch-stats per (t,col)
__global__ __launch_bounds__(256) void kprep(const float* __restrict__ gih0,
                                             const float* __restrict__ bih0,
                                             const float* __restrict__ b0) {
  const int t = blockIdx.x >> 5, ct = blockIdx.x & 31;    // grid 4096
  const int tid = threadIdx.x, w = tid >> 6, l = tid & 63;
  const int lm = l & 15, lq = l >> 4;
  __shared__ float sred[4][16][2];

  v8s bfi[3];
#pragma unroll
  for (int ks = 0; ks < 3; ++ks) bfi[ks] = ld8(&g_wtih0[(ct * 16 + lm) * KXP + ks * 32 + lq * 8]);

  const v4f vz = {0.f, 0.f, 0.f, 0.f};
  v4f acc[16];
#pragma unroll
  for (int mt = 0; mt < 16; ++mt) acc[mt] = vz;
#pragma unroll
  for (int mt = 0; mt < 16; ++mt) {
    const ush* ap = g_xpad + ((size_t)t * BB + w * 256 + mt * 16 + lm) * KXP + lq * 8;
#pragma unroll
    for (int ks = 0; ks < 3; ++ks)
      acc[mt] = __builtin_amdgcn_mfma_f32_16x16x32_bf16(ld8(ap + ks * 32), bfi[ks], acc[mt], 0, 0, 0);
  }
  float S = 0.f, Q = 0.f;
#pragma unroll
  for (int mt = 0; mt < 16; ++mt)
#pragma unroll
    for (int r = 0; r < 4; ++r) { float a = acc[mt][r]; S += a; Q += a * a; }
  S += __shfl_xor(S, 16); Q += __shfl_xor(Q, 16);
  S += __shfl_xor(S, 32); Q += __shfl_xor(Q, 32);
  if (l < 16) { sred[w][l][0] = S; sred[w][l][1] = Q; }
  __syncthreads();
  float Sa = 0.f, Qa = 0.f;
#pragma unroll
  for (int ww = 0; ww < 4; ++ww) { Sa += sred[ww][lm][0]; Qa += sred[ww][lm][1]; }
  const int col = ct * 16 + lm;
  float m_ = Sa * (1.f / BB), v_ = Qa * (1.f / BB) - m_ * m_;
  float a_ = gih0[col] * rsqrtf(v_ + EPSB);
  float d_ = bih0[col] - a_ * m_ + b0[col];
  ush* dst = g_G1c + ((size_t)(t * 512 + col)) * BB;
#pragma unroll
  for (int mt = 0; mt < 16; ++mt) {
    u32 p0 = (u32)f2bf(a_ * acc[mt][0] + d_) | ((u32)f2bf(a_ * acc[mt][1] + d_) << 16);
    u32 p1 = (u32)f2bf(a_ * acc[mt][2] + d_) | ((u32)f2bf(a_ * acc[mt][3] + d_) << 16);
    uint2 pk; pk.x = p0; pk.y = p1;
    *reinterpret_cast<uint2*>(dst + w * 256 + mt * 16 + lq * 4) = pk;
  }
}

// ---- fused persistent recurrent kernel: 32 blocks x 256 thr; block owns 32 batch rows, BOTH layers ----
__global__ __launch_bounds__(256, 1) void krec_fused(
    const float* __restrict__ ghh0, const float* __restrict__ bhh0,
    const float* __restrict__ gc0,  const float* __restrict__ bc0,
    const float* __restrict__ gih1, const float* __restrict__ bih1,
    const float* __restrict__ ghh1, const float* __restrict__ bhh1,
    const float* __restrict__ gc1,  const float* __restrict__ bc1,
    const float* __restrict__ b1) {
  const int tid = threadIdx.x;
  const int w = tid >> 6, l = tid & 63;
  const int lm = l & 15, lq = l >> 4;
  const int nb = blockIdx.x, row0 = nb * ROWS;

  __shared__ ush h0t[ROWS][136];   // +8 pad: keeps 16B align, 2-way-free LDS banking
  __shared__ ush h1t[ROWS][136];

  for (int idx = tid; idx < ROWS * 136; idx += 256) {
    (&h0t[0][0])[idx] = 0; (&h1t[0][0])[idx] = 0;
  }
  __syncthreads();

  // per-lane unit params (units u = (w+4*i0)*16+lm)
  float gcv0[2], bcv0[2], gcv1[2], bcv1[2];
#pragma unroll
  for (int i0 = 0; i0 < 2; ++i0) {
    int u = (w + 4 * i0) * 16 + lm;
    gcv0[i0] = gc0[u]; bcv0[i0] = bc0[u];
    gcv1[i0] = gc1[u]; bcv1[i0] = bc1[u];
  }

  float c0st[2][2][4], c1st[2][2][4], so0[2][2][4], so1[2][2][4];
#pragma unroll
  for (int i0 = 0; i0 < 2; ++i0)
#pragma unroll
    for (int mt = 0; mt < 2; ++mt)
#pragma unroll
      for (int r = 0; r < 4; ++r) { c0st[i0][mt][r] = 0.f; c1st[i0][mt][r] = 0.f; }

  const v4f vz = {0.f, 0.f, 0.f, 0.f};

  for (int s = 0; s <= TT; ++s) {
    const int p = s & 1;
    // ================= PHASE A =================
    // G1 loads (independent; issued early)
    uint2 g1ld[2][4][2];
    if (s < TT) {
#pragma unroll
      for (int i0 = 0; i0 < 2; ++i0)
#pragma unroll
        for (int g = 0; g < 4; ++g) {
          int col = (w + 4 * i0) * 16 + lm + 128 * g;
#pragma unroll
          for (int mt = 0; mt < 2; ++mt)
            g1ld[i0][g][mt] = *reinterpret_cast<const uint2*>(
                g_G1c + ((size_t)(s * 512 + col)) * BB + row0 + mt * 16 + lq * 4);
        }
    }
    // A-frags from LDS h tiles
    v8s a0f[2][4], a1f[2][4];
#pragma unroll
    for (int mt = 0; mt < 2; ++mt)
#pragma unroll
      for (int ks = 0; ks < 4; ++ks) {
        a0f[mt][ks] = ld8(&h0t[mt * 16 + lm][ks * 32 + lq * 8]);
        a1f[mt][ks] = ld8(&h1t[mt * 16 + lm][ks * 32 + lq * 8]);
      }
    // 3 GEMM streams, accumulators resident
    v4f Ph0[2][8], Pi1[2][8], Ph1[2][8];
#pragma unroll
    for (int mt = 0; mt < 2; ++mt)
#pragma unroll
      for (int i = 0; i < 8; ++i) { Ph0[mt][i] = vz; Pi1[mt][i] = vz; Ph1[mt][i] = vz; }
#pragma unroll
    for (int i = 0; i < 8; ++i) {
      const int colb = (w + 4 * i) * 16 + lm;
      const ush* wp0 = g_wthh0 + colb * HH + lq * 8;
      const ush* wp1 = g_wtih1 + colb * HH + lq * 8;
      const ush* wp2 = g_wthh1 + colb * HH + lq * 8;
#pragma unroll
      for (int ks = 0; ks < 4; ++ks) {
        v8s bh0 = ld8(wp0 + ks * 32);
        v8s bi1 = ld8(wp1 + ks * 32);
        v8s bh1 = ld8(wp2 + ks * 32);
#pragma unroll
        for (int mt = 0; mt < 2; ++mt) {
          Ph0[mt][i] = __builtin_amdgcn_mfma_f32_16x16x32_bf16(a0f[mt][ks], bh0, Ph0[mt][i], 0, 0, 0);
          Pi1[mt][i] = __builtin_amdgcn_mfma_f32_16x16x32_bf16(a0f[mt][ks], bi1, Pi1[mt][i], 0, 0, 0);
          Ph1[mt][i] = __builtin_amdgcn_mfma_f32_16x16x32_bf16(a1f[mt][ks], bh1, Ph1[mt][i], 0, 0, 0);
        }
      }
    }
    // gate-stat partials (block has 32 rows) -> atomicAdd
#pragma unroll
    for (int i = 0; i < 8; ++i) {
      float S0 = 0.f, Q0 = 0.f, S1 = 0.f, Q1 = 0.f, S2 = 0.f, Q2 = 0.f;
#pragma unroll
      for (int mt = 0; mt < 2; ++mt)
#pragma unroll
        for (int r = 0; r < 4; ++r) {
          float a = Ph0[mt][i][r]; S0 += a; Q0 += a * a;
          float b = Pi1[mt][i][r]; S1 += b; Q1 += b * b;
          float c = Ph1[mt][i][r]; S2 += c; Q2 += c * c;
        }
      S0 += __shfl_xor(S0, 16); Q0 += __shfl_xor(Q0, 16);
      S1 += __shfl_xor(S1, 16); Q1 += __shfl_xor(Q1, 16);
      S2 += __shfl_xor(S2, 16); Q2 += __shfl_xor(Q2, 16);
      S0 += __shfl_xor(S0, 32); Q0 += __shfl_xor(Q0, 32);
      S1 += __shfl_xor(S1, 32); Q1 += __shfl_xor(Q1, 32);
      S2 += __shfl_xor(S2, 32); Q2 += __shfl_xor(Q2, 32);
      if (l < 16) {
        int col = (w + 4 * i) * 16 + lm;
        sadd(&g_stats[p][col * 2], S0);        sadd(&g_stats[p][col * 2 + 1], Q0);
        sadd(&g_stats[p][1024 + col * 2], S1); sadd(&g_stats[p][1024 + col * 2 + 1], Q1);
        sadd(&g_stats[p][2048 + col * 2], S2); sadd(&g_stats[p][2048 + col * 2 + 1], Q2);
      }
    }
    // ---- grid barrier A ----
    __builtin_amdgcn_s_waitcnt(0x0f70);   // vmcnt(0): drain this thread's adds
    __syncthreads();
    if (tid == 0) {
      __hip_atomic_fetch_add(&g_ctr2[2 * s], 1u, __ATOMIC_RELEASE, __HIP_MEMORY_SCOPE_AGENT);
      while (__hip_atomic_load(&g_ctr2[2 * s], __ATOMIC_RELAXED, __HIP_MEMORY_SCOPE_AGENT) < NBLK)
        __builtin_amdgcn_s_sleep(1);
    }
    __syncthreads();

    // ================= PHASE B =================
    float gA0[2][4], gD0[2][4], gAi[2][4], gAh[2][4], gD1[2][4];
#pragma unroll
    for (int i0 = 0; i0 < 2; ++i0)
#pragma unroll
      for (int g = 0; g < 4; ++g) {
        int col = (w + 4 * i0) * 16 + lm + 128 * g;
        float S = sload(&g_stats[p][col * 2]), Q = sload(&g_stats[p][col * 2 + 1]);
        float m_ = S * (1.f / BB), v_ = Q * (1.f / BB) - m_ * m_;
        float a = ghh0[col] * rsqrtf(v_ + EPSB);
        gA0[i0][g] = a; gD0[i0][g] = bhh0[col] - a * m_;
        S = sload(&g_stats[p][1024 + col * 2]); Q = sload(&g_stats[p][1024 + col * 2 + 1]);
        m_ = S * (1.f / BB); v_ = Q * (1.f / BB) - m_ * m_;
        float ai = gih1[col] * rsqrtf(v_ + EPSB);
        float d1 = bih1[col] - ai * m_ + b1[col];
        S = sload(&g_stats[p][2048 + col * 2]); Q = sload(&g_stats[p][2048 + col * 2 + 1]);
        m_ = S * (1.f / BB); v_ = Q * (1.f / BB) - m_ * m_;
        float ah = ghh1[col] * rsqrtf(v_ + EPSB);
        gAi[i0][g] = ai; gAh[i0][g] = ah; gD1[i0][g] = d1 + bhh1[col] - ah * m_;
      }
    float cS0[2] = {0.f, 0.f}, cQ0[2] = {0.f, 0.f}, cS1[2] = {0.f, 0.f}, cQ1[2] = {0.f, 0.f};
#pragma unroll
    for (int i0 = 0; i0 < 2; ++i0)
#pragma unroll
      for (int mt = 0; mt < 2; ++mt) {
        float g0v[4][4], gt1[4][4];
#pragma unroll
        for (int g = 0; g < 4; ++g) {
          uint2 pk = g1ld[i0][g][mt];
          float b0v[4] = { bf2f((ush)pk.x), bf2f((ush)(pk.x >> 16)),
                           bf2f((ush)pk.y), bf2f((ush)(pk.y >> 16)) };
#pragma unroll
          for (int r = 0; r < 4; ++r) {
            g0v[g][r] = b0v[r] + gA0[i0][g] * Ph0[mt][i0 + 2 * g][r] + gD0[i0][g];
            gt1[g][r] = gAi[i0][g] * Pi1[mt][i0 + 2 * g][r]
                      + gAh[i0][g] * Ph1[mt][i0 + 2 * g][r] + gD1[i0][g];
          }
        }
        if (s < TT) {
#pragma unroll
          for (int r = 0; r < 4; ++r) {
            float c1 = sigf(g0v[0][r]) * c0st[i0][mt][r] + sigf(g0v[1][r]) * tanhf_(g0v[3][r]);
            c0st[i0][mt][r] = c1; so0[i0][mt][r] = sigf(g0v[2][r]);
            cS0[i0] += c1; cQ0[i0] += c1 * c1;
          }
        }
        if (s > 0) {
#pragma unroll
          for (int r = 0; r < 4; ++r) {
            float c1 = sigf(gt1[0][r]) * c1st[i0][mt][r] + sigf(gt1[1][r]) * tanhf_(gt1[3][r]);
            c1st[i0][mt][r] = c1; so1[i0][mt][r] = sigf(gt1[2][r]);
            cS1[i0] += c1; cQ1[i0] += c1 * c1;
          }
        }
      }
    // c-stat partials
#pragma unroll
    for (int i0 = 0; i0 < 2; ++i0) {
      float a = cS0[i0], b = cQ0[i0], c = cS1[i0], d = cQ1[i0];
      a += __shfl_xor(a, 16); b += __shfl_xor(b, 16); c += __shfl_xor(c, 16); d += __shfl_xor(d, 16);
      a += __shfl_xor(a, 32); b += __shfl_xor(b, 32); c += __shfl_xor(c, 32); d += __shfl_xor(d, 32);
      if (l < 16) {
        int u = (w + 4 * i0) * 16 + lm;
        sadd(&g_stats[p][3072 + u * 2], a);       sadd(&g_stats[p][3072 + u * 2 + 1], b);
        sadd(&g_stats[p][3072 + 256 + u * 2], c); sadd(&g_stats[p][3072 + 256 + u * 2 + 1], d);
      }
    }
    // zero the OTHER parity's c-region (read last step; all blocks past barrier A)
    if (tid < 16) szero(&g_stats[1 - p][3072 + nb * 16 + tid]);
    // ---- grid barrier B ----
    __builtin_amdgcn_s_waitcnt(0x0f70);
    __syncthreads();
    if (tid == 0) {
      __hip_atomic_fetch_add(&g_ctr2[2 * s + 1], 1u, __ATOMIC_RELEASE, __HIP_MEMORY_SCOPE_AGENT);
      while (__hip_atomic_load(&g_ctr2[2 * s + 1], __ATOMIC_RELAXED, __HIP_MEMORY_SCOPE_AGENT) < NBLK)
        __builtin_amdgcn_s_sleep(1);
    }
    __syncthreads();

    // ================= PHASE C =================
#pragma unroll
    for (int i0 = 0; i0 < 2; ++i0) {
      const int u = (w + 4 * i0) * 16 + lm;
      if (s < TT) {
        float S = sload(&g_stats[p][3072 + u * 2]), Q = sload(&g_stats[p][3072 + u * 2 + 1]);
        float m_ = S * (1.f / BB), v_ = Q * (1.f / BB) - m_ * m_;
        float ac = gcv0[i0] * rsqrtf(v_ + EPSB), dc = bcv0[i0] - ac * m_;
#pragma unroll
        for (int mt = 0; mt < 2; ++mt)
#pragma unroll
          for (int r = 0; r < 4; ++r)
            h0t[mt * 16 + lq * 4 + r][u] = f2bf(so0[i0][mt][r] * tanhf_(ac * c0st[i0][mt][r] + dc));
      }
      if (s > 0) {
        float S = sload(&g_stats[p][3072 + 256 + u * 2]), Q = sload(&g_stats[p][3072 + 256 + u * 2 + 1]);
        float m_ = S * (1.f / BB), v_ = Q * (1.f / BB) - m_ * m_;
        float ac = gcv1[i0] * rsqrtf(v_ + EPSB), dc = bcv1[i0] - ac * m_;
#pragma unroll
        for (int mt = 0; mt < 2; ++mt)
#pragma unroll
          for (int r = 0; r < 4; ++r)
            h1t[mt * 16 + lq * 4 + r][u] = f2bf(so1[i0][mt][r] * tanhf_(ac * c1st[i0][mt][r] + dc));
      }
    }
    // zero this parity's gate-region (everyone read it in phase B)
    if (tid < 96) szero(&g_stats[p][nb * 96 + tid]);
    __syncthreads();   // h tiles visible to next phase A
  }

  // write final h1(T-1) rows
  {
    int row = tid >> 3, k0 = (tid & 7) << 4;
    uint4 v0 = *reinterpret_cast<uint4*>(&h1t[row][k0]);
    uint4 v1 = *reinterpret_cast<uint4*>(&h1t[row][k0 + 8]);
    *reinterpret_cast<uint4*>(g_hlast + (size_t)(row0 + row) * HH + k0) = v0;
    *reinterpret_cast<uint4*>(g_hlast + (size_t)(row0 + row) * HH + k0 + 8) = v1;
  }
}

// ---- epilogue: emb = h_last @ fc_w + fc_b (bf16 out) ----
__global__ __launch_bounds__(256) void kfc(const float* __restrict__ fcb) {
  const int tid = threadIdx.x, w = tid >> 6, l = tid & 63;
  const int lm = l & 15, lq = l >> 4;
  const int col = blockIdx.x * 16 + lm;   // grid 16
  v8s bf[4];
#pragma unroll
  for (int ks = 0; ks < 4; ++ks) bf[ks] = ld8(&g_fcwt[col * HH + ks * 32 + lq * 8]);
  const float bias = fcb[col];
  const v4f vz = {0.f, 0.f, 0.f, 0.f};
#pragma unroll
  for (int mt = 0; mt < 16; ++mt) {
    const int rowa = w * 256 + mt * 16 + lm;
    const ush* ap = g_hlast + (size_t)rowa * HH + lq * 8;
    v4f acc = vz;
#pragma unroll
    for (int ks = 0; ks < 4; ++ks)
      acc = __builtin_amdgcn_mfma_f32_16x16x32_bf16(ld8(ap + ks * 32), bf[ks], acc, 0, 0, 0);
#pragma unroll
    for (int r = 0; r < 4; ++r) {
      int row = w * 256 + mt * 16 + lq * 4 + r;
      g_emb[row * OUTN + col] = f2bf(acc[r] + bias);
    }
  }
}

// ---- epilogue: out = emb @ dec_w + dec_b (fp32 out) ----
__global__ __launch_bounds__(256) void kdec(const float* __restrict__ decb, float* __restrict__ out) {
  const int tid = threadIdx.x, w = tid >> 6, l = tid & 63;
  const int lm = l & 15, lq = l >> 4;
  const int col = blockIdx.x * 16 + lm;   // grid 600
  v8s bf[8];
#pragma unroll
  for (int ks = 0; ks < 8; ++ks) bf[ks] = ld8(&g_decwt[(size_t)col * OUTN + ks * 32 + lq * 8]);
  const float bias = decb[col];
  const v4f vz = {0.f, 0.f, 0.f, 0.f};
#pragma unroll
  for (int mt = 0; mt < 16; ++mt) {
    const int rowa = w * 256 + mt * 16 + lm;
    const ush* ap = g_emb + (size_t)rowa * OUTN + lq * 8;
    v4f acc = vz;
#pragma unroll
    for (int ks = 0; ks < 8; ++ks)
      acc = __builtin_amdgcn_mfma_f32_16x16x32_bf16(ld8(ap + ks * 32), bf[ks], acc, 0, 0, 0);
#pragma unroll
    for (int r = 0; r < 4; ++r) {
      int row = w * 256 + mt * 16 + lq * 4 + r;
      out[(size_t)row * DECN + col] = acc[r] + bias;
    }
  }
}

extern "C" void kernel_launch(void* const* d_in, const int* in_sizes, int n_in,
                              void* d_out, int out_size, void* d_ws, size_t ws_size,
                              hipStream_t stream) {
  const float* seq  = (const float*)d_in[0];
  const float* Wih0 = (const float*)d_in[1];
  const float* Whh0 = (const float*)d_in[2];
  const float* b0   = (const float*)d_in[3];
  const float* gih0 = (const float*)d_in[4];
  const float* bih0 = (const float*)d_in[5];
  const float* ghh0 = (const float*)d_in[6];
  const float* bhh0 = (const float*)d_in[7];
  const float* gc0  = (const float*)d_in[8];
  const float* bc0  = (const float*)d_in[9];
  const float* Wih1 = (const float*)d_in[10];
  const float* Whh1 = (const float*)d_in[11];
  const float* b1   = (const float*)d_in[12];
  const float* gih1 = (const float*)d_in[13];
  const float* bih1 = (const float*)d_in[14];
  const float* ghh1 = (const float*)d_in[15];
  const float* bhh1 = (const float*)d_in[16];
  const float* gc1  = (const float*)d_in[17];
  const float* bc1  = (const float*)d_in[18];
  const float* fcw  = (const float*)d_in[19];
  const float* fcb  = (const float*)d_in[20];
  const float* decw = (const float*)d_in[21];
  const float* decb = (const float*)d_in[22];
  float* out = (float*)d_out;
  (void)in_sizes; (void)n_in; (void)out_size; (void)d_ws; (void)ws_size;

  kzero<<<dim3(32), dim3(256), 0, stream>>>();
  kpackx<<<dim3((TT * BB * KXP) / 256), dim3(256), 0, stream>>>(seq);
  kpackw<<<dim3(10688), dim3(256), 0, stream>>>(Wih0, Whh0, Wih1, Whh1, fcw, decw);
  kprep<<<dim3(TT * 32), dim3(256), 0, stream>>>(gih0, bih0, b0);
  krec_fused<<<dim3(NBLK), dim3(256), 0, stream>>>(ghh0, bhh0, gc0, bc0,
                                                   gih1, bih1, ghh1, bhh1, gc1, bc1, b1);
  kfc<<<dim3(16), dim3(256), 0, stream>>>(fcb);
  kdec<<<dim3(600), dim3(256), 0, stream>>>(decb, out);
}